// Round 10
// baseline (615.464 us; speedup 1.0000x reference)
//
#include <hip/hip_runtime.h>
#include <hip/hip_bf16.h>
#include <math.h>

// Problem constants
#define KF   7      // frames / groups
#define BB_  4      // batch
#define CC_  64     // channels per frame
#define HH   96
#define WW   96
#define HWSZ 9216   // 96*96
#define HEAD 256
#define CH2  448    // channels-last width of X2

typedef __bf16 bf16x8 __attribute__((ext_vector_type(8)));
typedef __bf16 bf16x4 __attribute__((ext_vector_type(4)));
typedef float  f32x4  __attribute__((ext_vector_type(4)));
typedef float  f32x2  __attribute__((ext_vector_type(2)));
typedef unsigned int u32;

// Packed fp32 helpers (VOP3P) + bf16 pack/unpack
__device__ __forceinline__ f32x2 pkmul(f32x2 a, f32x2 b) {
    f32x2 d; asm("v_pk_mul_f32 %0, %1, %2" : "=v"(d) : "v"(a), "v"(b)); return d;
}
__device__ __forceinline__ f32x2 pkfma(f32x2 a, f32x2 b, f32x2 c) {
    f32x2 d; asm("v_pk_fma_f32 %0, %1, %2, %3" : "=v"(d) : "v"(a), "v"(b), "v"(c)); return d;
}
__device__ __forceinline__ u32 cvtpk_bf16(f32x2 a) {
    u32 d; asm("v_cvt_pk_bf16_f32 %0, %1, %2" : "=v"(d) : "v"(a[0]), "v"(a[1])); return d;
}
__device__ __forceinline__ f32x2 unpk_bf16x2(u32 v) {
    f32x2 r;
    r[0] = __uint_as_float(v << 16);
    r[1] = __uint_as_float(v & 0xffff0000u);
    return r;
}

// ---------------------------------------------------------------------------
// ONE prep dispatch: cvt_feat + all weight transforms, branch by block range.
// Weight layout: chunk-interleaved (coalesced wave reads):
//   conv taps: [((tap*KC + ci/32)*CoutPad + co)*32 + ci%32]   (KC = Cin/32)
//   dcnA     : [((k/32)*256 + co)*32 + k%32],  k = g*576+tap*64+c
// off taps CoutPad = 256 (8 waves x 32 rows tile M cleanly); pad rows
// [189,256) never written -> garbage lands only in discarded D rows.
// ---------------------------------------------------------------------------
__device__ __forceinline__ void taps_body(const float* __restrict__ w,
                                          __bf16* __restrict__ out,
                                          int Cout, int Cin, int CoutPad, int e) {
    int tot = Cout * Cin * 9;
    if (e >= tot) return;
    int co = e / (Cin * 9);
    int r  = e - co * (Cin * 9);
    int ci = r / 9;
    int k  = r - ci * 9;
    int kc = ci >> 5, cw = ci & 31;
    out[(((size_t)k * (Cin >> 5) + kc) * CoutPad + co) * 32 + cw] = (__bf16)w[e];
}

__global__ __launch_bounds__(256) void prep_all(
    const float* __restrict__ feat, __bf16* __restrict__ X2,
    const float* __restrict__ wh_w1, __bf16* __restrict__ wh_wT2,
    const float* __restrict__ hm_w1, __bf16* __restrict__ hm_wT2,
    const float* __restrict__ id_w1, __bf16* __restrict__ id_wT2,
    const float* __restrict__ off_w, __bf16* __restrict__ off_wT2,
    const float* __restrict__ wh_w2, __bf16* __restrict__ wh_w2b,
    const float* __restrict__ hm_w2, __bf16* __restrict__ hm_w2b,
    const float* __restrict__ id_w2, __bf16* __restrict__ id_w2b,
    const float* __restrict__ bz_w,  __bf16* __restrict__ bz_wb,
    const float* __restrict__ dcn_w, __bf16* __restrict__ dcn_wA)
{
    __shared__ float sT[96][65];
    const int bid = blockIdx.x;
    const int t   = threadIdx.x;

    if (bid < 2688) {
        // ---- cvt_feat: (K,B,C,H,W) fp32 -> X2[b][h][w][g*64+c] bf16 -------
        const int h = bid % 96;
        const int n = bid / 96;          // g*4+b
        const int g = n >> 2, b = n & 3;
        const float* src = feat + (size_t)n * 64 * HWSZ + h * WW;
        for (int e = t; e < 6144; e += 256) {
            int c = e / 96, w = e - c * 96;
            sT[w][c] = src[(size_t)c * HWSZ + w];
        }
        __syncthreads();
        for (int u = t; u < 768; u += 256) {     // unit = 8 channels of one w
            int w = u >> 3, c8 = (u & 7) * 8;
            __bf16 tmp[8];
#pragma unroll
            for (int i = 0; i < 8; ++i) tmp[i] = (__bf16)sT[w][c8 + i];
            *(uint4*)&X2[(((size_t)(b * 96 + h)) * 96 + w) * CH2 + g * 64 + c8] =
                *(const uint4*)tmp;
        }
        return;
    }

    if (bid < 3264) { taps_body(wh_w1, wh_wT2, 256, 64, 256, (bid - 2688) * 256 + t); return; }
    if (bid < 3840) { taps_body(hm_w1, hm_wT2, 256, 64, 256, (bid - 3264) * 256 + t); return; }
    if (bid < 7872) { taps_body(id_w1, id_wT2, 256, 448, 256, (bid - 3840) * 256 + t); return; }
    if (bid < 10849){ taps_body(off_w, off_wT2, 189, 448, 256, (bid - 7872) * 256 + t); return; }
    if (bid < 10851){ int e = (bid - 10849) * 256 + t; if (e < 512)   wh_w2b[e] = (__bf16)wh_w2[e]; return; }
    if (bid < 10875){ int e = (bid - 10851) * 256 + t; if (e < 6144)  hm_w2b[e] = (__bf16)hm_w2[e]; return; }
    if (bid < 11003){ int e = (bid - 10875) * 256 + t; if (e < 32768) id_w2b[e] = (__bf16)id_w2[e]; return; }
    if (bid < 11019){ int e = (bid - 11003) * 256 + t; if (e < 4096)  bz_wb[e]  = (__bf16)bz_w[e];  return; }
    {   // dcnA: k = g*576+tap*64+c; dst [(k/32)*256 + co]*32 + k%32
        int e = (bid - 11019) * 256 + t;
        if (e >= 256 * 4032) return;
        int co = e / 4032;
        int r  = e - co * 4032;          // r = k index
        int g  = r / 576;
        int r2 = r - g * 576;
        int tap = r2 >> 6;
        int c   = r2 & 63;
        dcn_wA[((size_t)(r >> 5) * 256 + co) * 32 + (r & 31)] =
            (__bf16)dcn_w[((size_t)co * 448 + g * 64 + c) * 9 + tap];
    }
}

// ---------------------------------------------------------------------------
// MFMA conv3x3 (+bias,+relu) -> optional MFMA 1x1 (+bias).
// 512-thread / 8-wave / MPW=2; double-buffered async-stage (round-9 measured
// body, unchanged).  MODE 2 waves with mbase >= Cf skip the MFMA loop.
// ---------------------------------------------------------------------------
template<int MPW, int MODE>
__device__ __forceinline__ void conv_body(
    char* smem,
    const __bf16* __restrict__ X2,
    const __bf16* __restrict__ wT2,   // [((tap*KC+kc)*CmidPad + co)*32 + cw]
    const float* __restrict__ b1,
    const __bf16* __restrict__ w2b,   // [cf*256 + co]
    const float* __restrict__ b2,
    float* __restrict__ out,
    int Cin, int CmidPad, int Cf, int chanBase, int whMap,
    int h, int img)
{
    __bf16 (*sX)[3][98][40] = (__bf16 (*)[3][98][40])smem;   // [2] dbuf

    const int t    = threadIdx.x;
    const int wave = t >> 6;              // 0..7
    const int lane = t & 63;
    const int lq   = lane >> 4;
    const int lr   = lane & 15;
    const int mbase = wave * (MPW * 16);  // MPW=2 -> 32 rows/wave, 256 total

    const int bImg = whMap ? (img & 3) : img;
    const int cb   = whMap ? ((img >> 2) * 64) : chanBase;
    const __bf16* Xrow = X2 + ((size_t)bImg * 96) * 96 * CH2;

    const bool doGemm = (MODE != 2) || (mbase < Cf);

    f32x4 acc[MPW][6];
#pragma unroll
    for (int mi = 0; mi < MPW; ++mi)
#pragma unroll
        for (int ni = 0; ni < 6; ++ni)
            acc[mi][ni] = (f32x4){0.f, 0.f, 0.f, 0.f};

    const int KC = Cin >> 5;

    // ---- prolog: stage chunk 0 directly into buf 0 ------------------------
    for (int u = t; u < 1176; u += 512) {
        int pos = u >> 2;
        int q   = u & 3;
        int r   = pos / 98;
        int gw  = pos - r * 98;
        int gh  = h - 1 + r;
        int gx  = gw - 1;
        uint4 v = {0u, 0u, 0u, 0u};
        if (((unsigned)gh < 96u) && ((unsigned)gx < 96u))
            v = *(const uint4*)&Xrow[((size_t)gh * 96 + gx) * CH2 + cb + q * 8];
        *(uint4*)&sX[0][r][gw][q * 8] = v;
    }
    __syncthreads();

    for (int kc = 0; kc < KC; ++kc) {
        // ---- issue prefetch loads for chunk kc+1 into registers -----------
        uint4 pv[3];
        if (kc + 1 < KC) {
#pragma unroll
            for (int i = 0; i < 3; ++i) {
                int u = t + i * 512;
                uint4 v = {0u, 0u, 0u, 0u};
                if (u < 1176) {
                    int pos = u >> 2;
                    int q   = u & 3;
                    int r   = pos / 98;
                    int gw  = pos - r * 98;
                    int gh  = h - 1 + r;
                    int gx  = gw - 1;
                    if (((unsigned)gh < 96u) && ((unsigned)gx < 96u))
                        v = *(const uint4*)&Xrow[((size_t)gh * 96 + gx) * CH2 +
                                                 cb + (kc + 1) * 32 + q * 8];
                }
                pv[i] = v;
            }
        }
        asm volatile("" ::: "memory");   // pin load-issue before the GEMM

        // ---- GEMM(kc) on buf[kc&1] ----------------------------------------
        const int buf = kc & 1;
        if (doGemm) {
            const __bf16* wkc = wT2 + ((size_t)kc * CmidPad + mbase + lr) * 32 + lq * 8;
            const size_t tapStride = (size_t)KC * CmidPad * 32;
#pragma unroll
            for (int tap = 0; tap < 9; ++tap) {
                const int ky = tap / 3, kx = tap - ky * 3;
                const __bf16* wt = wkc + (size_t)tap * tapStride;
                bf16x8 aF[MPW];
#pragma unroll
                for (int mi = 0; mi < MPW; ++mi)
                    aF[mi] = *(const bf16x8*)(wt + mi * 512);   // mi*16 rows * 32
#pragma unroll
                for (int ni = 0; ni < 6; ++ni) {
                    bf16x8 bF = *(const bf16x8*)&sX[buf][ky][ni * 16 + lr + kx][lq * 8];
#pragma unroll
                    for (int mi = 0; mi < MPW; ++mi)
                        acc[mi][ni] = __builtin_amdgcn_mfma_f32_16x16x32_bf16(
                            aF[mi], bF, acc[mi][ni], 0, 0, 0);
                }
            }
        }

        // ---- write prefetched chunk into the other buffer -----------------
        if (kc + 1 < KC) {
#pragma unroll
            for (int i = 0; i < 3; ++i) {
                int u = t + i * 512;
                if (u < 1176) {
                    int pos = u >> 2;
                    int q   = u & 3;
                    int r   = pos / 98;
                    int gw  = pos - r * 98;
                    *(uint4*)&sX[buf ^ 1][r][gw][q * 8] = pv[i];
                }
            }
        }
        __syncthreads();
    }

    if (MODE == 2) {
#pragma unroll
        for (int mi = 0; mi < MPW; ++mi)
#pragma unroll
            for (int ni = 0; ni < 6; ++ni) {
                int px = ni * 16 + lr;
#pragma unroll
                for (int r = 0; r < 4; ++r) {
                    int co = mbase + mi * 16 + lq * 4 + r;
                    if (co < Cf)
                        out[((size_t)(img * 189 + co)) * HWSZ + h * WW + px] =
                            acc[mi][ni][r] + b1[co];
                }
            }
        return;
    } else {
        __syncthreads();
        __bf16 (*sH)[264] = (__bf16 (*)[264])smem;
#pragma unroll
        for (int mi = 0; mi < MPW; ++mi) {
            int co0 = mbase + mi * 16 + lq * 4;
            float bb0 = b1[co0], bb1 = b1[co0 + 1], bb2 = b1[co0 + 2], bb3 = b1[co0 + 3];
#pragma unroll
            for (int ni = 0; ni < 6; ++ni) {
                int px = ni * 16 + lr;
                bf16x4 hv;
                hv[0] = (__bf16)fmaxf(acc[mi][ni][0] + bb0, 0.f);
                hv[1] = (__bf16)fmaxf(acc[mi][ni][1] + bb1, 0.f);
                hv[2] = (__bf16)fmaxf(acc[mi][ni][2] + bb2, 0.f);
                hv[3] = (__bf16)fmaxf(acc[mi][ni][3] + bb3, 0.f);
                *(bf16x4*)&sH[px][co0] = hv;
            }
        }
        __syncthreads();

        const int MT2 = (Cf + 15) >> 4;
        for (int tt = wave; tt < MT2 * 6; tt += 8) {
            int ni = tt / MT2;
            int mt = tt - ni * MT2;
            int cf = mt * 16 + lr; if (cf > Cf - 1) cf = Cf - 1;
            const __bf16* wrow = w2b + (size_t)cf * 256 + lq * 8;
            f32x4 c = (f32x4){0.f, 0.f, 0.f, 0.f};
#pragma unroll
            for (int kc = 0; kc < 8; ++kc) {
                bf16x8 aF = *(const bf16x8*)(wrow + kc * 32);
                bf16x8 bF = *(const bf16x8*)&sH[ni * 16 + lr][kc * 32 + lq * 8];
                c = __builtin_amdgcn_mfma_f32_16x16x32_bf16(aF, bF, c, 0, 0, 0);
            }
            int px = ni * 16 + lr;
#pragma unroll
            for (int r = 0; r < 4; ++r) {
                int cfr = mt * 16 + lq * 4 + r;
                if (cfr < Cf) {
                    int och;
                    if (MODE == 1) {
                        och = (img & 3) * 14 + (img >> 2) * 2 + cfr;
                    } else {
                        och = img * Cf + cfr;
                    }
                    out[(size_t)och * HWSZ + h * WW + px] = c[r] + b2[cfr];
                }
            }
        }
    }
}

// ---------------------------------------------------------------------------
// ALL four conv branches in ONE dispatch.  512 threads (8 waves), MPW=2.
// __launch_bounds__(512,6): 6 waves/EU = 24 waves/CU = 3 blocks (exactly the
// LDS limit, 3*50688 <= 160K).  VGPR cap ~85; round-9 measured use = 64.
//   y 0..3 id | y 4..7 off | y 8..35 wh | y 36..39 hm
// ---------------------------------------------------------------------------
__global__ __launch_bounds__(512, 6) void conv_all(
    const __bf16* __restrict__ X2,
    const __bf16* __restrict__ idT, const float* __restrict__ id_b1,
    const __bf16* __restrict__ id_w2b, const float* __restrict__ id_b2,
    float* __restrict__ out_id,
    const __bf16* __restrict__ offT, const float* __restrict__ off_b,
    float* __restrict__ off_out,
    const __bf16* __restrict__ whT, const float* __restrict__ wh_b1,
    const __bf16* __restrict__ wh_w2b, const float* __restrict__ wh_b2,
    float* __restrict__ out_wh,
    const __bf16* __restrict__ hmT, const float* __restrict__ hm_b1,
    const __bf16* __restrict__ hm_w2b, const float* __restrict__ hm_b2,
    float* __restrict__ out_hm)
{
    __shared__ __align__(16) char smem[50688];
    const int h = blockIdx.x;
    const int y = blockIdx.y;
    if (y < 4)
        conv_body<2, 0>(smem, X2, idT, id_b1, id_w2b, id_b2, out_id,
                        448, 256, 128, 0, 0, h, y);
    else if (y < 8)
        conv_body<2, 2>(smem, X2, offT, off_b, nullptr, nullptr, off_out,
                        448, 256, 189, 0, 0, h, y - 4);
    else if (y < 36)
        conv_body<2, 1>(smem, X2, whT, wh_b1, wh_w2b, wh_b2, out_wh,
                        64, 256, 2, 0, 1, h, y - 8);
    else
        conv_body<2, 0>(smem, X2, hmT, hm_b1, hm_w2b, hm_b2, out_hm,
                        64, 256, 24, 192, 0, h, y - 36);
}

// ---------------------------------------------------------------------------
// DCNv2 via MFMA + bias + BN + ReLU + bz 1x1, fused.  Same 3-phase structure
// and layouts as the measured round-7 kernel; NOW 512 threads / 8 waves with
// M-tile 32/wave (acc[2][3]) -> 24 waves/CU (was 12).  Grid unchanged (768).
// ---------------------------------------------------------------------------
#define DNP 48
__global__ __launch_bounds__(512, 6) void dcn_bz_mfma(
    const __bf16* __restrict__ X2,
    const float* __restrict__ offmap,   // (B,189,H,W) fp32
    const __bf16* __restrict__ wA,      // [(k/32)*256 + co]*32 + k%32
    const float* __restrict__ dcn_b,
    const float* __restrict__ bn_g, const float* __restrict__ bn_be,
    const float* __restrict__ bn_mn, const float* __restrict__ bn_vr,
    const __bf16* __restrict__ bzwb,    // [16][256]
    const float* __restrict__ bzb,
    float* __restrict__ out_bz)
{
    __shared__ __align__(16) char smem[33600];
    __bf16 (*sC)[DNP][40] = (__bf16 (*)[DNP][40])smem;   // [6][48][40] staging
    __bf16 (*sD)[DNP][40] = (__bf16 (*)[DNP][40])smem;   // [8][48][40] epilogue
    float4* sW4   = (float4*)(smem + 30720);              // [144] corner weights
    int*    sWoff = (int*)  (smem + 30720 + 2304);        // [144] clamped base

    // XCD-aware bijective swizzle: dispatch order is x-fastest; fid%8 = XCD.
    const int fid = blockIdx.x + blockIdx.y * 192;
    const int nf  = (fid & 7) * 96 + (fid >> 3);
    const int b   = nf / 192;
    const int r_  = nf - b * 192;
    const int h   = r_ >> 1;
    const int w0  = (r_ & 1) * DNP;

    const int t    = threadIdx.x;
    const int wave = t >> 6;           // 0..7
    const int lane = t & 63;
    const int lq   = lane >> 4;
    const int lr   = lane & 15;
    const int mbase = wave * 32;       // 32 co rows per wave
    const int grp  = t >> 3;           // 8-lane gather group 0..63
    const int lsub = t & 7;

    const float* offp = offmap + (size_t)b * 189 * HWSZ;
    const __bf16* Xb  = X2 + ((size_t)b * 96) * 96 * CH2;

    f32x4 acc[2][3];
#pragma unroll
    for (int mi = 0; mi < 2; ++mi)
#pragma unroll
        for (int ni = 0; ni < 3; ++ni)
            acc[mi][ni] = (f32x4){0.f, 0.f, 0.f, 0.f};

    for (int g = 0; g < KF; ++g) {
        for (int c3 = 0; c3 < 3; ++c3) {
            __syncthreads();   // prev GEMM done with sC; sW reusable
            // ---- A: weights + base per (tap,px) pair, coalesced offmap ----
            if (t < 144) {
                int tl = t / 48;             // kx
                int px = t - tl * 48;
                int pix = h * WW + w0 + px;
                int gk  = g * 9 + c3 * 3 + tl;
                float oy = offp[(size_t)gk * HWSZ + pix];
                float ox = offp[(size_t)(63 + gk) * HWSZ + pix];
                float mv = offp[(size_t)(126 + gk) * HWSZ + pix];
                float m  = 1.f / (1.f + expf(-mv));
                float sy = (float)(h - 1 + c3) + oy;
                float sx = (float)(w0 + px - 1 + tl) + ox;
                float fy = floorf(sy), fx = floorf(sx);
                float wy = sy - fy,    wx = sx - fx;
                int y0 = (int)fy, x0 = (int)fx;
                int by = min(max(y0, 0), 94);
                int bx = min(max(x0, 0), 94);
                float wy0 = (y0 == by ? 1.f - wy : 0.f) + (y0 + 1 == by ? wy : 0.f);
                float wy1 = (y0 == by + 1 ? 1.f - wy : 0.f) + (y0 + 1 == by + 1 ? wy : 0.f);
                float wx0 = (x0 == bx ? 1.f - wx : 0.f) + (x0 + 1 == bx ? wx : 0.f);
                float wx1 = (x0 == bx + 1 ? 1.f - wx : 0.f) + (x0 + 1 == bx + 1 ? wx : 0.f);
                float4 wv;
                wv.x = m * wy0 * wx0; wv.y = m * wy0 * wx1;
                wv.z = m * wy1 * wx0; wv.w = m * wy1 * wx1;
                sW4[t]   = wv;
                sWoff[t] = by * 96 + bx;
            }
            __syncthreads();   // sW ready
            // ---- B: cooperative gather, 8 lanes = 64 ch of one pair -------
            // 64 groups cover 144 pairs (2-3 each)
            for (int p = grp; p < 144; p += 64) {
                float4 wv = sW4[p];
                int base  = sWoff[p];
                int tl = p / 48;
                int px = p - tl * 48;
                const __bf16* pl = Xb + (size_t)base * CH2 + g * 64 + lsub * 8;
                bf16x8 c00 = *(const bf16x8*)(pl);
                bf16x8 c01 = *(const bf16x8*)(pl + CH2);
                bf16x8 c10 = *(const bf16x8*)(pl + 96 * CH2);
                bf16x8 c11 = *(const bf16x8*)(pl + 97 * CH2);
                f32x2 vw00 = {wv.x, wv.x}, vw01 = {wv.y, wv.y};
                f32x2 vw10 = {wv.z, wv.z}, vw11 = {wv.w, wv.w};
                const u32* p00 = (const u32*)&c00;
                const u32* p01 = (const u32*)&c01;
                const u32* p10 = (const u32*)&c10;
                const u32* p11 = (const u32*)&c11;
                u32 o[4];
#pragma unroll
                for (int pp = 0; pp < 4; ++pp) {
                    f32x2 a = pkmul(vw00, unpk_bf16x2(p00[pp]));
                    a = pkfma(vw01, unpk_bf16x2(p01[pp]), a);
                    a = pkfma(vw10, unpk_bf16x2(p10[pp]), a);
                    a = pkfma(vw11, unpk_bf16x2(p11[pp]), a);
                    o[pp] = cvtpk_bf16(a);
                }
                int kc = tl * 2 + (lsub >> 2);
                *(uint4*)&sC[kc][px][(lsub & 3) * 8] = *(const uint4*)o;
            }
            __syncthreads();   // cols ready
            // ---- C: GEMM over this K=192 chunk (6 sub-chunks of 32) -------
            const __bf16* wbase = wA + ((size_t)(g * 18 + c3 * 6) * 256 +
                                        mbase + lr) * 32 + lq * 8;
#pragma unroll
            for (int kc = 0; kc < 6; ++kc) {
                const __bf16* wk = wbase + (size_t)kc * 256 * 32;
                bf16x8 aF[2];
#pragma unroll
                for (int mi = 0; mi < 2; ++mi)
                    aF[mi] = *(const bf16x8*)(wk + mi * 512);
#pragma unroll
                for (int ni = 0; ni < 3; ++ni) {
                    bf16x8 bF = *(const bf16x8*)&sC[kc][ni * 16 + lr][lq * 8];
#pragma unroll
                    for (int mi = 0; mi < 2; ++mi)
                        acc[mi][ni] = __builtin_amdgcn_mfma_f32_16x16x32_bf16(
                            aF[mi], bF, acc[mi][ni], 0, 0, 0);
                }
            }
        }
    }

    // ---- epilogue: bias + BN + relu -> channels-last bf16 LDS -------------
    __syncthreads();
#pragma unroll
    for (int mi = 0; mi < 2; ++mi) {
        int co0 = mbase + mi * 16 + lq * 4;
        float sc[4], sh[4];
#pragma unroll
        for (int r = 0; r < 4; ++r) {
            float s = bn_g[co0 + r] * rsqrtf(bn_vr[co0 + r] + 1e-5f);
            sc[r] = s;
            sh[r] = (dcn_b[co0 + r] - bn_mn[co0 + r]) * s + bn_be[co0 + r];
        }
#pragma unroll
        for (int ni = 0; ni < 3; ++ni) {
            int px = ni * 16 + lr;
            bf16x4 hv;
#pragma unroll
            for (int r = 0; r < 4; ++r)
                hv[r] = (__bf16)fmaxf(acc[mi][ni][r] * sc[r] + sh[r], 0.f);
            *(bf16x4*)&sD[co0 >> 5][px][co0 & 31] = hv;
        }
    }
    __syncthreads();

    // ---- bz 1x1: M=16, K=256, N=48 (3 n-tiles on waves 0..2) --------------
    if (wave < 3) {
        int ni = wave;
        const __bf16* wrow = bzwb + (size_t)lr * 256 + lq * 8;
        f32x4 c = (f32x4){0.f, 0.f, 0.f, 0.f};
#pragma unroll
        for (int kc = 0; kc < 8; ++kc) {
            bf16x8 aF = *(const bf16x8*)(wrow + kc * 32);
            bf16x8 bF = *(const bf16x8*)&sD[kc][ni * 16 + lr][lq * 8];
            c = __builtin_amdgcn_mfma_f32_16x16x32_bf16(aF, bF, c, 0, 0, 0);
        }
        int px = ni * 16 + lr;
#pragma unroll
        for (int r = 0; r < 4; ++r) {
            int cf = lq * 4 + r;
            out_bz[((size_t)(b * 16 + cf)) * HWSZ + h * WW + w0 + px] = c[r] + bzb[cf];
        }
    }
}

// ---------------------------------------------------------------------------
// Launch
// ---------------------------------------------------------------------------
extern "C" void kernel_launch(void* const* d_in, const int* in_sizes, int n_in,
                              void* d_out, int out_size, void* d_ws, size_t ws_size,
                              hipStream_t stream) {
    const float* feat   = (const float*)d_in[0];
    const float* hm_w1  = (const float*)d_in[1];
    const float* hm_b1  = (const float*)d_in[2];
    const float* hm_w2  = (const float*)d_in[3];
    const float* hm_b2  = (const float*)d_in[4];
    const float* wh_w1  = (const float*)d_in[5];
    const float* wh_b1  = (const float*)d_in[6];
    const float* wh_w2  = (const float*)d_in[7];
    const float* wh_b2  = (const float*)d_in[8];
    const float* id_w1  = (const float*)d_in[9];
    const float* id_b1  = (const float*)d_in[10];
    const float* id_w2  = (const float*)d_in[11];
    const float* id_b2  = (const float*)d_in[12];
    const float* off_w  = (const float*)d_in[13];
    const float* off_b  = (const float*)d_in[14];
    const float* dcn_w  = (const float*)d_in[15];
    const float* dcn_b  = (const float*)d_in[16];
    const float* bn_g   = (const float*)d_in[17];
    const float* bn_be  = (const float*)d_in[18];
    const float* bn_mn  = (const float*)d_in[19];
    const float* bn_vr  = (const float*)d_in[20];
    const float* bz_w   = (const float*)d_in[21];
    const float* bz_b   = (const float*)d_in[22];

    // Workspace layout (off_wT2 CoutPad=256: 1,032,192)
    float* ws      = (float*)d_ws;
    float* off_out = ws;                        // 6,967,296 f (27.9 MB)
    __bf16* X2     = (__bf16*)(off_out + 6967296); // 16,515,072 bf16
    __bf16* bfw    = X2 + 16515072;
    __bf16* wh_wT2 = bfw;                       // 147,456
    __bf16* hm_wT2 = wh_wT2 + 147456;           // 147,456
    __bf16* id_wT2 = hm_wT2 + 147456;           // 1,032,192
    __bf16* off_wT2= id_wT2 + 1032192;          // 1,032,192 (padded)
    __bf16* wh_w2b = off_wT2 + 1032192;         //     512
    __bf16* hm_w2b = wh_w2b + 512;              //    6144
    __bf16* id_w2b = hm_w2b + 6144;             //   32768
    __bf16* dcn_wA = id_w2b + 32768;            // 1,032,192
    __bf16* bz_wb  = dcn_wA + 1032192;          //    4096

    // Output layout (floats, concatenated): hm, bz, idout, owh
    float* out_hm = (float*)d_out;              // (4,24,96,96)
    float* out_bz = out_hm + 884736;            // (4,16,96,96)
    float* out_id = out_bz + 589824;            // (4,128,96,96)
    float* out_wh = out_id + 4718592;           // (4,14,96,96)

    // 1) ONE prep dispatch (feat conversion + all weight transforms)
    prep_all<<<15051, 256, 0, stream>>>(
        feat, X2,
        wh_w1, wh_wT2, hm_w1, hm_wT2, id_w1, id_wT2, off_w, off_wT2,
        wh_w2, wh_w2b, hm_w2, hm_w2b, id_w2, id_w2b, bz_w, bz_wb,
        dcn_w, dcn_wA);

    // 2) ALL conv branches in one dispatch (8-wave MPW=2, 24 waves/CU)
    conv_all<<<dim3(96, 40), 512, 0, stream>>>(
        X2,
        id_wT2, id_b1, id_w2b, id_b2, out_id,
        off_wT2, off_b, off_out,
        wh_wT2, wh_b1, wh_w2b, wh_b2, out_wh,
        hm_wT2, hm_b1, hm_w2b, hm_b2, out_hm);

    // 3) DCN via MFMA + BN + ReLU + bz (512 threads, 24 waves/CU)
    dcn_bz_mfma<<<dim3(192, 4), 512, 0, stream>>>(
        X2, off_out, dcn_wA, dcn_b, bn_g, bn_be, bn_mn, bn_vr,
        bz_wb, bz_b, out_bz);
}

// Round 11
// 565.942 us; speedup vs baseline: 1.0875x; 1.0875x over previous
//
#include <hip/hip_runtime.h>
#include <hip/hip_bf16.h>
#include <math.h>

// Problem constants
#define KF   7      // frames / groups
#define BB_  4      // batch
#define CC_  64     // channels per frame
#define HH   96
#define WW   96
#define HWSZ 9216   // 96*96
#define HEAD 256
#define CH2  448    // channels-last width of X2

typedef __bf16 bf16x8 __attribute__((ext_vector_type(8)));
typedef __bf16 bf16x4 __attribute__((ext_vector_type(4)));
typedef float  f32x4  __attribute__((ext_vector_type(4)));
typedef float  f32x2  __attribute__((ext_vector_type(2)));
typedef unsigned int u32;

// Packed fp32 helpers (VOP3P) + bf16 pack/unpack
__device__ __forceinline__ f32x2 pkmul(f32x2 a, f32x2 b) {
    f32x2 d; asm("v_pk_mul_f32 %0, %1, %2" : "=v"(d) : "v"(a), "v"(b)); return d;
}
__device__ __forceinline__ f32x2 pkfma(f32x2 a, f32x2 b, f32x2 c) {
    f32x2 d; asm("v_pk_fma_f32 %0, %1, %2, %3" : "=v"(d) : "v"(a), "v"(b), "v"(c)); return d;
}
__device__ __forceinline__ u32 cvtpk_bf16(f32x2 a) {
    u32 d; asm("v_cvt_pk_bf16_f32 %0, %1, %2" : "=v"(d) : "v"(a[0]), "v"(a[1])); return d;
}
__device__ __forceinline__ f32x2 unpk_bf16x2(u32 v) {
    f32x2 r;
    r[0] = __uint_as_float(v << 16);
    r[1] = __uint_as_float(v & 0xffff0000u);
    return r;
}

// ---------------------------------------------------------------------------
// ONE prep dispatch: cvt_feat + all weight transforms, branch by block range.
// Weight layout: chunk-interleaved (coalesced wave reads):
//   conv taps: [((tap*KC + ci/32)*CoutPad + co)*32 + ci%32]   (KC = Cin/32)
//   dcnA     : [((k/32)*256 + co)*32 + k%32],  k = g*576+tap*64+c
// off taps CoutPad = 256 (8 waves x 32 rows tile M cleanly); pad rows
// [189,256) never written -> garbage lands only in discarded D rows.
// ---------------------------------------------------------------------------
__device__ __forceinline__ void taps_body(const float* __restrict__ w,
                                          __bf16* __restrict__ out,
                                          int Cout, int Cin, int CoutPad, int e) {
    int tot = Cout * Cin * 9;
    if (e >= tot) return;
    int co = e / (Cin * 9);
    int r  = e - co * (Cin * 9);
    int ci = r / 9;
    int k  = r - ci * 9;
    int kc = ci >> 5, cw = ci & 31;
    out[(((size_t)k * (Cin >> 5) + kc) * CoutPad + co) * 32 + cw] = (__bf16)w[e];
}

__global__ __launch_bounds__(256) void prep_all(
    const float* __restrict__ feat, __bf16* __restrict__ X2,
    const float* __restrict__ wh_w1, __bf16* __restrict__ wh_wT2,
    const float* __restrict__ hm_w1, __bf16* __restrict__ hm_wT2,
    const float* __restrict__ id_w1, __bf16* __restrict__ id_wT2,
    const float* __restrict__ off_w, __bf16* __restrict__ off_wT2,
    const float* __restrict__ wh_w2, __bf16* __restrict__ wh_w2b,
    const float* __restrict__ hm_w2, __bf16* __restrict__ hm_w2b,
    const float* __restrict__ id_w2, __bf16* __restrict__ id_w2b,
    const float* __restrict__ bz_w,  __bf16* __restrict__ bz_wb,
    const float* __restrict__ dcn_w, __bf16* __restrict__ dcn_wA)
{
    __shared__ float sT[96][65];
    const int bid = blockIdx.x;
    const int t   = threadIdx.x;

    if (bid < 2688) {
        // ---- cvt_feat: (K,B,C,H,W) fp32 -> X2[b][h][w][g*64+c] bf16 -------
        const int h = bid % 96;
        const int n = bid / 96;          // g*4+b
        const int g = n >> 2, b = n & 3;
        const float* src = feat + (size_t)n * 64 * HWSZ + h * WW;
        for (int e = t; e < 6144; e += 256) {
            int c = e / 96, w = e - c * 96;
            sT[w][c] = src[(size_t)c * HWSZ + w];
        }
        __syncthreads();
        for (int u = t; u < 768; u += 256) {     // unit = 8 channels of one w
            int w = u >> 3, c8 = (u & 7) * 8;
            __bf16 tmp[8];
#pragma unroll
            for (int i = 0; i < 8; ++i) tmp[i] = (__bf16)sT[w][c8 + i];
            *(uint4*)&X2[(((size_t)(b * 96 + h)) * 96 + w) * CH2 + g * 64 + c8] =
                *(const uint4*)tmp;
        }
        return;
    }

    if (bid < 3264) { taps_body(wh_w1, wh_wT2, 256, 64, 256, (bid - 2688) * 256 + t); return; }
    if (bid < 3840) { taps_body(hm_w1, hm_wT2, 256, 64, 256, (bid - 3264) * 256 + t); return; }
    if (bid < 7872) { taps_body(id_w1, id_wT2, 256, 448, 256, (bid - 3840) * 256 + t); return; }
    if (bid < 10849){ taps_body(off_w, off_wT2, 189, 448, 256, (bid - 7872) * 256 + t); return; }
    if (bid < 10851){ int e = (bid - 10849) * 256 + t; if (e < 512)   wh_w2b[e] = (__bf16)wh_w2[e]; return; }
    if (bid < 10875){ int e = (bid - 10851) * 256 + t; if (e < 6144)  hm_w2b[e] = (__bf16)hm_w2[e]; return; }
    if (bid < 11003){ int e = (bid - 10875) * 256 + t; if (e < 32768) id_w2b[e] = (__bf16)id_w2[e]; return; }
    if (bid < 11019){ int e = (bid - 11003) * 256 + t; if (e < 4096)  bz_wb[e]  = (__bf16)bz_w[e];  return; }
    {   // dcnA: k = g*576+tap*64+c; dst [(k/32)*256 + co]*32 + k%32
        int e = (bid - 11019) * 256 + t;
        if (e >= 256 * 4032) return;
        int co = e / 4032;
        int r  = e - co * 4032;          // r = k index
        int g  = r / 576;
        int r2 = r - g * 576;
        int tap = r2 >> 6;
        int c   = r2 & 63;
        dcn_wA[((size_t)(r >> 5) * 256 + co) * 32 + (r & 31)] =
            (__bf16)dcn_w[((size_t)co * 448 + g * 64 + c) * 9 + tap];
    }
}

// ---------------------------------------------------------------------------
// MFMA conv3x3 (+bias,+relu) -> optional MFMA 1x1 (+bias).
// 512-thread / 8-wave / MPW=2; double-buffered async-stage (round-9 measured
// body, unchanged).  MODE 2 waves with mbase >= Cf skip the MFMA loop.
// ---------------------------------------------------------------------------
template<int MPW, int MODE>
__device__ __forceinline__ void conv_body(
    char* smem,
    const __bf16* __restrict__ X2,
    const __bf16* __restrict__ wT2,   // [((tap*KC+kc)*CmidPad + co)*32 + cw]
    const float* __restrict__ b1,
    const __bf16* __restrict__ w2b,   // [cf*256 + co]
    const float* __restrict__ b2,
    float* __restrict__ out,
    int Cin, int CmidPad, int Cf, int chanBase, int whMap,
    int h, int img)
{
    __bf16 (*sX)[3][98][40] = (__bf16 (*)[3][98][40])smem;   // [2] dbuf

    const int t    = threadIdx.x;
    const int wave = t >> 6;              // 0..7
    const int lane = t & 63;
    const int lq   = lane >> 4;
    const int lr   = lane & 15;
    const int mbase = wave * (MPW * 16);  // MPW=2 -> 32 rows/wave, 256 total

    const int bImg = whMap ? (img & 3) : img;
    const int cb   = whMap ? ((img >> 2) * 64) : chanBase;
    const __bf16* Xrow = X2 + ((size_t)bImg * 96) * 96 * CH2;

    const bool doGemm = (MODE != 2) || (mbase < Cf);

    f32x4 acc[MPW][6];
#pragma unroll
    for (int mi = 0; mi < MPW; ++mi)
#pragma unroll
        for (int ni = 0; ni < 6; ++ni)
            acc[mi][ni] = (f32x4){0.f, 0.f, 0.f, 0.f};

    const int KC = Cin >> 5;

    // ---- prolog: stage chunk 0 directly into buf 0 ------------------------
    for (int u = t; u < 1176; u += 512) {
        int pos = u >> 2;
        int q   = u & 3;
        int r   = pos / 98;
        int gw  = pos - r * 98;
        int gh  = h - 1 + r;
        int gx  = gw - 1;
        uint4 v = {0u, 0u, 0u, 0u};
        if (((unsigned)gh < 96u) && ((unsigned)gx < 96u))
            v = *(const uint4*)&Xrow[((size_t)gh * 96 + gx) * CH2 + cb + q * 8];
        *(uint4*)&sX[0][r][gw][q * 8] = v;
    }
    __syncthreads();

    for (int kc = 0; kc < KC; ++kc) {
        // ---- issue prefetch loads for chunk kc+1 into registers -----------
        uint4 pv[3];
        if (kc + 1 < KC) {
#pragma unroll
            for (int i = 0; i < 3; ++i) {
                int u = t + i * 512;
                uint4 v = {0u, 0u, 0u, 0u};
                if (u < 1176) {
                    int pos = u >> 2;
                    int q   = u & 3;
                    int r   = pos / 98;
                    int gw  = pos - r * 98;
                    int gh  = h - 1 + r;
                    int gx  = gw - 1;
                    if (((unsigned)gh < 96u) && ((unsigned)gx < 96u))
                        v = *(const uint4*)&Xrow[((size_t)gh * 96 + gx) * CH2 +
                                                 cb + (kc + 1) * 32 + q * 8];
                }
                pv[i] = v;
            }
        }
        asm volatile("" ::: "memory");   // pin load-issue before the GEMM

        // ---- GEMM(kc) on buf[kc&1] ----------------------------------------
        const int buf = kc & 1;
        if (doGemm) {
            const __bf16* wkc = wT2 + ((size_t)kc * CmidPad + mbase + lr) * 32 + lq * 8;
            const size_t tapStride = (size_t)KC * CmidPad * 32;
#pragma unroll
            for (int tap = 0; tap < 9; ++tap) {
                const int ky = tap / 3, kx = tap - ky * 3;
                const __bf16* wt = wkc + (size_t)tap * tapStride;
                bf16x8 aF[MPW];
#pragma unroll
                for (int mi = 0; mi < MPW; ++mi)
                    aF[mi] = *(const bf16x8*)(wt + mi * 512);   // mi*16 rows * 32
#pragma unroll
                for (int ni = 0; ni < 6; ++ni) {
                    bf16x8 bF = *(const bf16x8*)&sX[buf][ky][ni * 16 + lr + kx][lq * 8];
#pragma unroll
                    for (int mi = 0; mi < MPW; ++mi)
                        acc[mi][ni] = __builtin_amdgcn_mfma_f32_16x16x32_bf16(
                            aF[mi], bF, acc[mi][ni], 0, 0, 0);
                }
            }
        }

        // ---- write prefetched chunk into the other buffer -----------------
        if (kc + 1 < KC) {
#pragma unroll
            for (int i = 0; i < 3; ++i) {
                int u = t + i * 512;
                if (u < 1176) {
                    int pos = u >> 2;
                    int q   = u & 3;
                    int r   = pos / 98;
                    int gw  = pos - r * 98;
                    *(uint4*)&sX[buf ^ 1][r][gw][q * 8] = pv[i];
                }
            }
        }
        __syncthreads();
    }

    if (MODE == 2) {
#pragma unroll
        for (int mi = 0; mi < MPW; ++mi)
#pragma unroll
            for (int ni = 0; ni < 6; ++ni) {
                int px = ni * 16 + lr;
#pragma unroll
                for (int r = 0; r < 4; ++r) {
                    int co = mbase + mi * 16 + lq * 4 + r;
                    if (co < Cf)
                        out[((size_t)(img * 189 + co)) * HWSZ + h * WW + px] =
                            acc[mi][ni][r] + b1[co];
                }
            }
        return;
    } else {
        __syncthreads();
        __bf16 (*sH)[264] = (__bf16 (*)[264])smem;
#pragma unroll
        for (int mi = 0; mi < MPW; ++mi) {
            int co0 = mbase + mi * 16 + lq * 4;
            float bb0 = b1[co0], bb1 = b1[co0 + 1], bb2 = b1[co0 + 2], bb3 = b1[co0 + 3];
#pragma unroll
            for (int ni = 0; ni < 6; ++ni) {
                int px = ni * 16 + lr;
                bf16x4 hv;
                hv[0] = (__bf16)fmaxf(acc[mi][ni][0] + bb0, 0.f);
                hv[1] = (__bf16)fmaxf(acc[mi][ni][1] + bb1, 0.f);
                hv[2] = (__bf16)fmaxf(acc[mi][ni][2] + bb2, 0.f);
                hv[3] = (__bf16)fmaxf(acc[mi][ni][3] + bb3, 0.f);
                *(bf16x4*)&sH[px][co0] = hv;
            }
        }
        __syncthreads();

        const int MT2 = (Cf + 15) >> 4;
        for (int tt = wave; tt < MT2 * 6; tt += 8) {
            int ni = tt / MT2;
            int mt = tt - ni * MT2;
            int cf = mt * 16 + lr; if (cf > Cf - 1) cf = Cf - 1;
            const __bf16* wrow = w2b + (size_t)cf * 256 + lq * 8;
            f32x4 c = (f32x4){0.f, 0.f, 0.f, 0.f};
#pragma unroll
            for (int kc = 0; kc < 8; ++kc) {
                bf16x8 aF = *(const bf16x8*)(wrow + kc * 32);
                bf16x8 bF = *(const bf16x8*)&sH[ni * 16 + lr][kc * 32 + lq * 8];
                c = __builtin_amdgcn_mfma_f32_16x16x32_bf16(aF, bF, c, 0, 0, 0);
            }
            int px = ni * 16 + lr;
#pragma unroll
            for (int r = 0; r < 4; ++r) {
                int cfr = mt * 16 + lq * 4 + r;
                if (cfr < Cf) {
                    int och;
                    if (MODE == 1) {
                        och = (img & 3) * 14 + (img >> 2) * 2 + cfr;
                    } else {
                        och = img * Cf + cfr;
                    }
                    out[(size_t)och * HWSZ + h * WW + px] = c[r] + b2[cfr];
                }
            }
        }
    }
}

// ---------------------------------------------------------------------------
// ALL four conv branches in ONE dispatch.  512 threads (8 waves), MPW=2.
// __launch_bounds__(512,4) — ROUND-9 MEASURED OPTIMUM (248 us, no spill).
// NOTE: true per-thread register need = 64 VGPR + ~48 AGPR = ~112 (unified
// file); (512,6)'s 85-cap spilled 555 MB in round 10.  Do not raise.
//   y 0..3 id | y 4..7 off | y 8..35 wh | y 36..39 hm
// ---------------------------------------------------------------------------
__global__ __launch_bounds__(512, 4) void conv_all(
    const __bf16* __restrict__ X2,
    const __bf16* __restrict__ idT, const float* __restrict__ id_b1,
    const __bf16* __restrict__ id_w2b, const float* __restrict__ id_b2,
    float* __restrict__ out_id,
    const __bf16* __restrict__ offT, const float* __restrict__ off_b,
    float* __restrict__ off_out,
    const __bf16* __restrict__ whT, const float* __restrict__ wh_b1,
    const __bf16* __restrict__ wh_w2b, const float* __restrict__ wh_b2,
    float* __restrict__ out_wh,
    const __bf16* __restrict__ hmT, const float* __restrict__ hm_b1,
    const __bf16* __restrict__ hm_w2b, const float* __restrict__ hm_b2,
    float* __restrict__ out_hm)
{
    __shared__ __align__(16) char smem[50688];
    const int h = blockIdx.x;
    const int y = blockIdx.y;
    if (y < 4)
        conv_body<2, 0>(smem, X2, idT, id_b1, id_w2b, id_b2, out_id,
                        448, 256, 128, 0, 0, h, y);
    else if (y < 8)
        conv_body<2, 2>(smem, X2, offT, off_b, nullptr, nullptr, off_out,
                        448, 256, 189, 0, 0, h, y - 4);
    else if (y < 36)
        conv_body<2, 1>(smem, X2, whT, wh_b1, wh_w2b, wh_b2, out_wh,
                        64, 256, 2, 0, 1, h, y - 8);
    else
        conv_body<2, 0>(smem, X2, hmT, hm_b1, hm_w2b, hm_b2, out_hm,
                        64, 256, 24, 192, 0, h, y - 36);
}

// ---------------------------------------------------------------------------
// DCNv2 via MFMA + bias + BN + ReLU + bz 1x1, fused.  512 threads / 8 waves,
// M-tile 32/wave (acc[2][3]) — correctness proven in round 10.  Plain
// __launch_bounds__(512): allocator takes what it needs (~80 unified regs),
// natural occupancy 5-6 waves/EU with NO spill risk.
// ---------------------------------------------------------------------------
#define DNP 48
__global__ __launch_bounds__(512) void dcn_bz_mfma(
    const __bf16* __restrict__ X2,
    const float* __restrict__ offmap,   // (B,189,H,W) fp32
    const __bf16* __restrict__ wA,      // [(k/32)*256 + co]*32 + k%32
    const float* __restrict__ dcn_b,
    const float* __restrict__ bn_g, const float* __restrict__ bn_be,
    const float* __restrict__ bn_mn, const float* __restrict__ bn_vr,
    const __bf16* __restrict__ bzwb,    // [16][256]
    const float* __restrict__ bzb,
    float* __restrict__ out_bz)
{
    __shared__ __align__(16) char smem[33600];
    __bf16 (*sC)[DNP][40] = (__bf16 (*)[DNP][40])smem;   // [6][48][40] staging
    __bf16 (*sD)[DNP][40] = (__bf16 (*)[DNP][40])smem;   // [8][48][40] epilogue
    float4* sW4   = (float4*)(smem + 30720);              // [144] corner weights
    int*    sWoff = (int*)  (smem + 30720 + 2304);        // [144] clamped base

    // XCD-aware bijective swizzle: dispatch order is x-fastest; fid%8 = XCD.
    const int fid = blockIdx.x + blockIdx.y * 192;
    const int nf  = (fid & 7) * 96 + (fid >> 3);
    const int b   = nf / 192;
    const int r_  = nf - b * 192;
    const int h   = r_ >> 1;
    const int w0  = (r_ & 1) * DNP;

    const int t    = threadIdx.x;
    const int wave = t >> 6;           // 0..7
    const int lane = t & 63;
    const int lq   = lane >> 4;
    const int lr   = lane & 15;
    const int mbase = wave * 32;       // 32 co rows per wave
    const int grp  = t >> 3;           // 8-lane gather group 0..63
    const int lsub = t & 7;

    const float* offp = offmap + (size_t)b * 189 * HWSZ;
    const __bf16* Xb  = X2 + ((size_t)b * 96) * 96 * CH2;

    f32x4 acc[2][3];
#pragma unroll
    for (int mi = 0; mi < 2; ++mi)
#pragma unroll
        for (int ni = 0; ni < 3; ++ni)
            acc[mi][ni] = (f32x4){0.f, 0.f, 0.f, 0.f};

    for (int g = 0; g < KF; ++g) {
        for (int c3 = 0; c3 < 3; ++c3) {
            __syncthreads();   // prev GEMM done with sC; sW reusable
            // ---- A: weights + base per (tap,px) pair, coalesced offmap ----
            if (t < 144) {
                int tl = t / 48;             // kx
                int px = t - tl * 48;
                int pix = h * WW + w0 + px;
                int gk  = g * 9 + c3 * 3 + tl;
                float oy = offp[(size_t)gk * HWSZ + pix];
                float ox = offp[(size_t)(63 + gk) * HWSZ + pix];
                float mv = offp[(size_t)(126 + gk) * HWSZ + pix];
                float m  = 1.f / (1.f + expf(-mv));
                float sy = (float)(h - 1 + c3) + oy;
                float sx = (float)(w0 + px - 1 + tl) + ox;
                float fy = floorf(sy), fx = floorf(sx);
                float wy = sy - fy,    wx = sx - fx;
                int y0 = (int)fy, x0 = (int)fx;
                int by = min(max(y0, 0), 94);
                int bx = min(max(x0, 0), 94);
                float wy0 = (y0 == by ? 1.f - wy : 0.f) + (y0 + 1 == by ? wy : 0.f);
                float wy1 = (y0 == by + 1 ? 1.f - wy : 0.f) + (y0 + 1 == by + 1 ? wy : 0.f);
                float wx0 = (x0 == bx ? 1.f - wx : 0.f) + (x0 + 1 == bx ? wx : 0.f);
                float wx1 = (x0 == bx + 1 ? 1.f - wx : 0.f) + (x0 + 1 == bx + 1 ? wx : 0.f);
                float4 wv;
                wv.x = m * wy0 * wx0; wv.y = m * wy0 * wx1;
                wv.z = m * wy1 * wx0; wv.w = m * wy1 * wx1;
                sW4[t]   = wv;
                sWoff[t] = by * 96 + bx;
            }
            __syncthreads();   // sW ready
            // ---- B: cooperative gather, 8 lanes = 64 ch of one pair -------
            // 64 groups cover 144 pairs (2-3 each)
            for (int p = grp; p < 144; p += 64) {
                float4 wv = sW4[p];
                int base  = sWoff[p];
                int tl = p / 48;
                int px = p - tl * 48;
                const __bf16* pl = Xb + (size_t)base * CH2 + g * 64 + lsub * 8;
                bf16x8 c00 = *(const bf16x8*)(pl);
                bf16x8 c01 = *(const bf16x8*)(pl + CH2);
                bf16x8 c10 = *(const bf16x8*)(pl + 96 * CH2);
                bf16x8 c11 = *(const bf16x8*)(pl + 97 * CH2);
                f32x2 vw00 = {wv.x, wv.x}, vw01 = {wv.y, wv.y};
                f32x2 vw10 = {wv.z, wv.z}, vw11 = {wv.w, wv.w};
                const u32* p00 = (const u32*)&c00;
                const u32* p01 = (const u32*)&c01;
                const u32* p10 = (const u32*)&c10;
                const u32* p11 = (const u32*)&c11;
                u32 o[4];
#pragma unroll
                for (int pp = 0; pp < 4; ++pp) {
                    f32x2 a = pkmul(vw00, unpk_bf16x2(p00[pp]));
                    a = pkfma(vw01, unpk_bf16x2(p01[pp]), a);
                    a = pkfma(vw10, unpk_bf16x2(p10[pp]), a);
                    a = pkfma(vw11, unpk_bf16x2(p11[pp]), a);
                    o[pp] = cvtpk_bf16(a);
                }
                int kc = tl * 2 + (lsub >> 2);
                *(uint4*)&sC[kc][px][(lsub & 3) * 8] = *(const uint4*)o;
            }
            __syncthreads();   // cols ready
            // ---- C: GEMM over this K=192 chunk (6 sub-chunks of 32) -------
            const __bf16* wbase = wA + ((size_t)(g * 18 + c3 * 6) * 256 +
                                        mbase + lr) * 32 + lq * 8;
#pragma unroll
            for (int kc = 0; kc < 6; ++kc) {
                const __bf16* wk = wbase + (size_t)kc * 256 * 32;
                bf16x8 aF[2];
#pragma unroll
                for (int mi = 0; mi < 2; ++mi)
                    aF[mi] = *(const bf16x8*)(wk + mi * 512);
#pragma unroll
                for (int ni = 0; ni < 3; ++ni) {
                    bf16x8 bF = *(const bf16x8*)&sC[kc][ni * 16 + lr][lq * 8];
#pragma unroll
                    for (int mi = 0; mi < 2; ++mi)
                        acc[mi][ni] = __builtin_amdgcn_mfma_f32_16x16x32_bf16(
                            aF[mi], bF, acc[mi][ni], 0, 0, 0);
                }
            }
        }
    }

    // ---- epilogue: bias + BN + relu -> channels-last bf16 LDS -------------
    __syncthreads();
#pragma unroll
    for (int mi = 0; mi < 2; ++mi) {
        int co0 = mbase + mi * 16 + lq * 4;
        float sc[4], sh[4];
#pragma unroll
        for (int r = 0; r < 4; ++r) {
            float s = bn_g[co0 + r] * rsqrtf(bn_vr[co0 + r] + 1e-5f);
            sc[r] = s;
            sh[r] = (dcn_b[co0 + r] - bn_mn[co0 + r]) * s + bn_be[co0 + r];
        }
#pragma unroll
        for (int ni = 0; ni < 3; ++ni) {
            int px = ni * 16 + lr;
            bf16x4 hv;
#pragma unroll
            for (int r = 0; r < 4; ++r)
                hv[r] = (__bf16)fmaxf(acc[mi][ni][r] * sc[r] + sh[r], 0.f);
            *(bf16x4*)&sD[co0 >> 5][px][co0 & 31] = hv;
        }
    }
    __syncthreads();

    // ---- bz 1x1: M=16, K=256, N=48 (3 n-tiles on waves 0..2) --------------
    if (wave < 3) {
        int ni = wave;
        const __bf16* wrow = bzwb + (size_t)lr * 256 + lq * 8;
        f32x4 c = (f32x4){0.f, 0.f, 0.f, 0.f};
#pragma unroll
        for (int kc = 0; kc < 8; ++kc) {
            bf16x8 aF = *(const bf16x8*)(wrow + kc * 32);
            bf16x8 bF = *(const bf16x8*)&sD[kc][ni * 16 + lr][lq * 8];
            c = __builtin_amdgcn_mfma_f32_16x16x32_bf16(aF, bF, c, 0, 0, 0);
        }
        int px = ni * 16 + lr;
#pragma unroll
        for (int r = 0; r < 4; ++r) {
            int cf = lq * 4 + r;
            out_bz[((size_t)(b * 16 + cf)) * HWSZ + h * WW + w0 + px] = c[r] + bzb[cf];
        }
    }
}

// ---------------------------------------------------------------------------
// Launch
// ---------------------------------------------------------------------------
extern "C" void kernel_launch(void* const* d_in, const int* in_sizes, int n_in,
                              void* d_out, int out_size, void* d_ws, size_t ws_size,
                              hipStream_t stream) {
    const float* feat   = (const float*)d_in[0];
    const float* hm_w1  = (const float*)d_in[1];
    const float* hm_b1  = (const float*)d_in[2];
    const float* hm_w2  = (const float*)d_in[3];
    const float* hm_b2  = (const float*)d_in[4];
    const float* wh_w1  = (const float*)d_in[5];
    const float* wh_b1  = (const float*)d_in[6];
    const float* wh_w2  = (const float*)d_in[7];
    const float* wh_b2  = (const float*)d_in[8];
    const float* id_w1  = (const float*)d_in[9];
    const float* id_b1  = (const float*)d_in[10];
    const float* id_w2  = (const float*)d_in[11];
    const float* id_b2  = (const float*)d_in[12];
    const float* off_w  = (const float*)d_in[13];
    const float* off_b  = (const float*)d_in[14];
    const float* dcn_w  = (const float*)d_in[15];
    const float* dcn_b  = (const float*)d_in[16];
    const float* bn_g   = (const float*)d_in[17];
    const float* bn_be  = (const float*)d_in[18];
    const float* bn_mn  = (const float*)d_in[19];
    const float* bn_vr  = (const float*)d_in[20];
    const float* bz_w   = (const float*)d_in[21];
    const float* bz_b   = (const float*)d_in[22];

    // Workspace layout (off_wT2 CoutPad=256: 1,032,192)
    float* ws      = (float*)d_ws;
    float* off_out = ws;                        // 6,967,296 f (27.9 MB)
    __bf16* X2     = (__bf16*)(off_out + 6967296); // 16,515,072 bf16
    __bf16* bfw    = X2 + 16515072;
    __bf16* wh_wT2 = bfw;                       // 147,456
    __bf16* hm_wT2 = wh_wT2 + 147456;           // 147,456
    __bf16* id_wT2 = hm_wT2 + 147456;           // 1,032,192
    __bf16* off_wT2= id_wT2 + 1032192;          // 1,032,192 (padded)
    __bf16* wh_w2b = off_wT2 + 1032192;         //     512
    __bf16* hm_w2b = wh_w2b + 512;              //    6144
    __bf16* id_w2b = hm_w2b + 6144;             //   32768
    __bf16* dcn_wA = id_w2b + 32768;            // 1,032,192
    __bf16* bz_wb  = dcn_wA + 1032192;          //    4096

    // Output layout (floats, concatenated): hm, bz, idout, owh
    float* out_hm = (float*)d_out;              // (4,24,96,96)
    float* out_bz = out_hm + 884736;            // (4,16,96,96)
    float* out_id = out_bz + 589824;            // (4,128,96,96)
    float* out_wh = out_id + 4718592;           // (4,14,96,96)

    // 1) ONE prep dispatch (feat conversion + all weight transforms)
    prep_all<<<15051, 256, 0, stream>>>(
        feat, X2,
        wh_w1, wh_wT2, hm_w1, hm_wT2, id_w1, id_wT2, off_w, off_wT2,
        wh_w2, wh_w2b, hm_w2, hm_w2b, id_w2, id_w2b, bz_w, bz_wb,
        dcn_w, dcn_wA);

    // 2) ALL conv branches in one dispatch (8-wave MPW=2, (512,4) = round-9)
    conv_all<<<dim3(96, 40), 512, 0, stream>>>(
        X2,
        id_wT2, id_b1, id_w2b, id_b2, out_id,
        off_wT2, off_b, off_out,
        wh_wT2, wh_b1, wh_w2b, wh_b2, out_wh,
        hm_wT2, hm_b1, hm_w2b, hm_b2, out_hm);

    // 3) DCN via MFMA + BN + ReLU + bz (512 threads, natural occupancy)
    dcn_bz_mfma<<<dim3(192, 4), 512, 0, stream>>>(
        X2, off_out, dcn_wA, dcn_b, bn_g, bn_be, bn_mn, bn_vr,
        bz_wb, bz_b, out_bz);
}

// Round 12
// 500.783 us; speedup vs baseline: 1.2290x; 1.1301x over previous
//
#include <hip/hip_runtime.h>
#include <hip/hip_bf16.h>
#include <math.h>

// Problem constants
#define KF   7      // frames / groups
#define BB_  4      // batch
#define CC_  64     // channels per frame
#define HH   96
#define WW   96
#define HWSZ 9216   // 96*96
#define HEAD 256
#define CH2  448    // channels-last width of X2

typedef __bf16 bf16x8 __attribute__((ext_vector_type(8)));
typedef __bf16 bf16x4 __attribute__((ext_vector_type(4)));
typedef float  f32x4  __attribute__((ext_vector_type(4)));
typedef float  f32x2  __attribute__((ext_vector_type(2)));
typedef unsigned int u32;

// Packed fp32 helpers (VOP3P) + bf16 pack/unpack
__device__ __forceinline__ f32x2 pkmul(f32x2 a, f32x2 b) {
    f32x2 d; asm("v_pk_mul_f32 %0, %1, %2" : "=v"(d) : "v"(a), "v"(b)); return d;
}
__device__ __forceinline__ f32x2 pkfma(f32x2 a, f32x2 b, f32x2 c) {
    f32x2 d; asm("v_pk_fma_f32 %0, %1, %2, %3" : "=v"(d) : "v"(a), "v"(b), "v"(c)); return d;
}
__device__ __forceinline__ u32 cvtpk_bf16(f32x2 a) {
    u32 d; asm("v_cvt_pk_bf16_f32 %0, %1, %2" : "=v"(d) : "v"(a[0]), "v"(a[1])); return d;
}
__device__ __forceinline__ f32x2 unpk_bf16x2(u32 v) {
    f32x2 r;
    r[0] = __uint_as_float(v << 16);
    r[1] = __uint_as_float(v & 0xffff0000u);
    return r;
}

// ---------------------------------------------------------------------------
// ONE prep dispatch: cvt_feat + all weight transforms, branch by block range.
// Weight layout: chunk-interleaved (coalesced wave reads):
//   conv taps: [((tap*KC + ci/32)*CoutPad + co)*32 + ci%32]   (KC = Cin/32)
//   dcnA     : [((k/32)*256 + co)*32 + k%32],  k = g*576+tap*64+c
// off taps CoutPad = 256; pad rows [189,256) never written.
// ---------------------------------------------------------------------------
__device__ __forceinline__ void taps_body(const float* __restrict__ w,
                                          __bf16* __restrict__ out,
                                          int Cout, int Cin, int CoutPad, int e) {
    int tot = Cout * Cin * 9;
    if (e >= tot) return;
    int co = e / (Cin * 9);
    int r  = e - co * (Cin * 9);
    int ci = r / 9;
    int k  = r - ci * 9;
    int kc = ci >> 5, cw = ci & 31;
    out[(((size_t)k * (Cin >> 5) + kc) * CoutPad + co) * 32 + cw] = (__bf16)w[e];
}

__global__ __launch_bounds__(256) void prep_all(
    const float* __restrict__ feat, __bf16* __restrict__ X2,
    const float* __restrict__ wh_w1, __bf16* __restrict__ wh_wT2,
    const float* __restrict__ hm_w1, __bf16* __restrict__ hm_wT2,
    const float* __restrict__ id_w1, __bf16* __restrict__ id_wT2,
    const float* __restrict__ off_w, __bf16* __restrict__ off_wT2,
    const float* __restrict__ wh_w2, __bf16* __restrict__ wh_w2b,
    const float* __restrict__ hm_w2, __bf16* __restrict__ hm_w2b,
    const float* __restrict__ id_w2, __bf16* __restrict__ id_w2b,
    const float* __restrict__ bz_w,  __bf16* __restrict__ bz_wb,
    const float* __restrict__ dcn_w, __bf16* __restrict__ dcn_wA)
{
    __shared__ float sT[96][65];
    const int bid = blockIdx.x;
    const int t   = threadIdx.x;

    if (bid < 2688) {
        // ---- cvt_feat: (K,B,C,H,W) fp32 -> X2[b][h][w][g*64+c] bf16 -------
        const int h = bid % 96;
        const int n = bid / 96;          // g*4+b
        const int g = n >> 2, b = n & 3;
        const float* src = feat + (size_t)n * 64 * HWSZ + h * WW;
        for (int e = t; e < 6144; e += 256) {
            int c = e / 96, w = e - c * 96;
            sT[w][c] = src[(size_t)c * HWSZ + w];
        }
        __syncthreads();
        for (int u = t; u < 768; u += 256) {     // unit = 8 channels of one w
            int w = u >> 3, c8 = (u & 7) * 8;
            __bf16 tmp[8];
#pragma unroll
            for (int i = 0; i < 8; ++i) tmp[i] = (__bf16)sT[w][c8 + i];
            *(uint4*)&X2[(((size_t)(b * 96 + h)) * 96 + w) * CH2 + g * 64 + c8] =
                *(const uint4*)tmp;
        }
        return;
    }

    if (bid < 3264) { taps_body(wh_w1, wh_wT2, 256, 64, 256, (bid - 2688) * 256 + t); return; }
    if (bid < 3840) { taps_body(hm_w1, hm_wT2, 256, 64, 256, (bid - 3264) * 256 + t); return; }
    if (bid < 7872) { taps_body(id_w1, id_wT2, 256, 448, 256, (bid - 3840) * 256 + t); return; }
    if (bid < 10849){ taps_body(off_w, off_wT2, 189, 448, 256, (bid - 7872) * 256 + t); return; }
    if (bid < 10851){ int e = (bid - 10849) * 256 + t; if (e < 512)   wh_w2b[e] = (__bf16)wh_w2[e]; return; }
    if (bid < 10875){ int e = (bid - 10851) * 256 + t; if (e < 6144)  hm_w2b[e] = (__bf16)hm_w2[e]; return; }
    if (bid < 11003){ int e = (bid - 10875) * 256 + t; if (e < 32768) id_w2b[e] = (__bf16)id_w2[e]; return; }
    if (bid < 11019){ int e = (bid - 11003) * 256 + t; if (e < 4096)  bz_wb[e]  = (__bf16)bz_w[e];  return; }
    {   // dcnA: k = g*576+tap*64+c; dst [(k/32)*256 + co]*32 + k%32
        int e = (bid - 11019) * 256 + t;
        if (e >= 256 * 4032) return;
        int co = e / 4032;
        int r  = e - co * 4032;          // r = k index
        int g  = r / 576;
        int r2 = r - g * 576;
        int tap = r2 >> 6;
        int c   = r2 & 63;
        dcn_wA[((size_t)(r >> 5) * 256 + co) * 32 + (r & 31)] =
            (__bf16)dcn_w[((size_t)co * 448 + g * 64 + c) * 9 + tap];
    }
}

// ---------------------------------------------------------------------------
// MFMA conv3x3 (+bias,+relu) -> optional MFMA 1x1 (+bias).
// 512-thread / 8-wave / MPW=2; double-buffered async-stage (round-9 measured
// body, unchanged).  MODE 2 waves with mbase >= Cf skip the MFMA loop.
// ---------------------------------------------------------------------------
template<int MPW, int MODE>
__device__ __forceinline__ void conv_body(
    char* smem,
    const __bf16* __restrict__ X2,
    const __bf16* __restrict__ wT2,   // [((tap*KC+kc)*CmidPad + co)*32 + cw]
    const float* __restrict__ b1,
    const __bf16* __restrict__ w2b,   // [cf*256 + co]
    const float* __restrict__ b2,
    float* __restrict__ out,
    int Cin, int CmidPad, int Cf, int chanBase, int whMap,
    int h, int img)
{
    __bf16 (*sX)[3][98][40] = (__bf16 (*)[3][98][40])smem;   // [2] dbuf

    const int t    = threadIdx.x;
    const int wave = t >> 6;              // 0..7
    const int lane = t & 63;
    const int lq   = lane >> 4;
    const int lr   = lane & 15;
    const int mbase = wave * (MPW * 16);  // MPW=2 -> 32 rows/wave, 256 total

    const int bImg = whMap ? (img & 3) : img;
    const int cb   = whMap ? ((img >> 2) * 64) : chanBase;
    const __bf16* Xrow = X2 + ((size_t)bImg * 96) * 96 * CH2;

    const bool doGemm = (MODE != 2) || (mbase < Cf);

    f32x4 acc[MPW][6];
#pragma unroll
    for (int mi = 0; mi < MPW; ++mi)
#pragma unroll
        for (int ni = 0; ni < 6; ++ni)
            acc[mi][ni] = (f32x4){0.f, 0.f, 0.f, 0.f};

    const int KC = Cin >> 5;

    // ---- prolog: stage chunk 0 directly into buf 0 ------------------------
    for (int u = t; u < 1176; u += 512) {
        int pos = u >> 2;
        int q   = u & 3;
        int r   = pos / 98;
        int gw  = pos - r * 98;
        int gh  = h - 1 + r;
        int gx  = gw - 1;
        uint4 v = {0u, 0u, 0u, 0u};
        if (((unsigned)gh < 96u) && ((unsigned)gx < 96u))
            v = *(const uint4*)&Xrow[((size_t)gh * 96 + gx) * CH2 + cb + q * 8];
        *(uint4*)&sX[0][r][gw][q * 8] = v;
    }
    __syncthreads();

    for (int kc = 0; kc < KC; ++kc) {
        // ---- issue prefetch loads for chunk kc+1 into registers -----------
        uint4 pv[3];
        if (kc + 1 < KC) {
#pragma unroll
            for (int i = 0; i < 3; ++i) {
                int u = t + i * 512;
                uint4 v = {0u, 0u, 0u, 0u};
                if (u < 1176) {
                    int pos = u >> 2;
                    int q   = u & 3;
                    int r   = pos / 98;
                    int gw  = pos - r * 98;
                    int gh  = h - 1 + r;
                    int gx  = gw - 1;
                    if (((unsigned)gh < 96u) && ((unsigned)gx < 96u))
                        v = *(const uint4*)&Xrow[((size_t)gh * 96 + gx) * CH2 +
                                                 cb + (kc + 1) * 32 + q * 8];
                }
                pv[i] = v;
            }
        }
        asm volatile("" ::: "memory");   // pin load-issue before the GEMM

        // ---- GEMM(kc) on buf[kc&1] ----------------------------------------
        const int buf = kc & 1;
        if (doGemm) {
            const __bf16* wkc = wT2 + ((size_t)kc * CmidPad + mbase + lr) * 32 + lq * 8;
            const size_t tapStride = (size_t)KC * CmidPad * 32;
#pragma unroll
            for (int tap = 0; tap < 9; ++tap) {
                const int ky = tap / 3, kx = tap - ky * 3;
                const __bf16* wt = wkc + (size_t)tap * tapStride;
                bf16x8 aF[MPW];
#pragma unroll
                for (int mi = 0; mi < MPW; ++mi)
                    aF[mi] = *(const bf16x8*)(wt + mi * 512);   // mi*16 rows * 32
#pragma unroll
                for (int ni = 0; ni < 6; ++ni) {
                    bf16x8 bF = *(const bf16x8*)&sX[buf][ky][ni * 16 + lr + kx][lq * 8];
#pragma unroll
                    for (int mi = 0; mi < MPW; ++mi)
                        acc[mi][ni] = __builtin_amdgcn_mfma_f32_16x16x32_bf16(
                            aF[mi], bF, acc[mi][ni], 0, 0, 0);
                }
            }
        }

        // ---- write prefetched chunk into the other buffer -----------------
        if (kc + 1 < KC) {
#pragma unroll
            for (int i = 0; i < 3; ++i) {
                int u = t + i * 512;
                if (u < 1176) {
                    int pos = u >> 2;
                    int q   = u & 3;
                    int r   = pos / 98;
                    int gw  = pos - r * 98;
                    *(uint4*)&sX[buf ^ 1][r][gw][q * 8] = pv[i];
                }
            }
        }
        __syncthreads();
    }

    if (MODE == 2) {
#pragma unroll
        for (int mi = 0; mi < MPW; ++mi)
#pragma unroll
            for (int ni = 0; ni < 6; ++ni) {
                int px = ni * 16 + lr;
#pragma unroll
                for (int r = 0; r < 4; ++r) {
                    int co = mbase + mi * 16 + lq * 4 + r;
                    if (co < Cf)
                        out[((size_t)(img * 189 + co)) * HWSZ + h * WW + px] =
                            acc[mi][ni][r] + b1[co];
                }
            }
        return;
    } else {
        __syncthreads();
        __bf16 (*sH)[264] = (__bf16 (*)[264])smem;
#pragma unroll
        for (int mi = 0; mi < MPW; ++mi) {
            int co0 = mbase + mi * 16 + lq * 4;
            float bb0 = b1[co0], bb1 = b1[co0 + 1], bb2 = b1[co0 + 2], bb3 = b1[co0 + 3];
#pragma unroll
            for (int ni = 0; ni < 6; ++ni) {
                int px = ni * 16 + lr;
                bf16x4 hv;
                hv[0] = (__bf16)fmaxf(acc[mi][ni][0] + bb0, 0.f);
                hv[1] = (__bf16)fmaxf(acc[mi][ni][1] + bb1, 0.f);
                hv[2] = (__bf16)fmaxf(acc[mi][ni][2] + bb2, 0.f);
                hv[3] = (__bf16)fmaxf(acc[mi][ni][3] + bb3, 0.f);
                *(bf16x4*)&sH[px][co0] = hv;
            }
        }
        __syncthreads();

        const int MT2 = (Cf + 15) >> 4;
        for (int tt = wave; tt < MT2 * 6; tt += 8) {
            int ni = tt / MT2;
            int mt = tt - ni * MT2;
            int cf = mt * 16 + lr; if (cf > Cf - 1) cf = Cf - 1;
            const __bf16* wrow = w2b + (size_t)cf * 256 + lq * 8;
            f32x4 c = (f32x4){0.f, 0.f, 0.f, 0.f};
#pragma unroll
            for (int kc = 0; kc < 8; ++kc) {
                bf16x8 aF = *(const bf16x8*)(wrow + kc * 32);
                bf16x8 bF = *(const bf16x8*)&sH[ni * 16 + lr][kc * 32 + lq * 8];
                c = __builtin_amdgcn_mfma_f32_16x16x32_bf16(aF, bF, c, 0, 0, 0);
            }
            int px = ni * 16 + lr;
#pragma unroll
            for (int r = 0; r < 4; ++r) {
                int cfr = mt * 16 + lq * 4 + r;
                if (cfr < Cf) {
                    int och;
                    if (MODE == 1) {
                        och = (img & 3) * 14 + (img >> 2) * 2 + cfr;
                    } else {
                        och = img * Cf + cfr;
                    }
                    out[(size_t)och * HWSZ + h * WW + px] = c[r] + b2[cfr];
                }
            }
        }
    }
}

// ---------------------------------------------------------------------------
// ALL four conv branches in ONE dispatch.  512 threads (8 waves), MPW=2.
// __launch_bounds__(512,4) — ROUND-9/11 MEASURED OPTIMUM (250 us, no spill).
// True register need = 64 VGPR + ~48 AGPR = ~112 unified; (512,6) spills.
//   y 0..3 id | y 4..7 off | y 8..35 wh | y 36..39 hm
// ---------------------------------------------------------------------------
__global__ __launch_bounds__(512, 4) void conv_all(
    const __bf16* __restrict__ X2,
    const __bf16* __restrict__ idT, const float* __restrict__ id_b1,
    const __bf16* __restrict__ id_w2b, const float* __restrict__ id_b2,
    float* __restrict__ out_id,
    const __bf16* __restrict__ offT, const float* __restrict__ off_b,
    float* __restrict__ off_out,
    const __bf16* __restrict__ whT, const float* __restrict__ wh_b1,
    const __bf16* __restrict__ wh_w2b, const float* __restrict__ wh_b2,
    float* __restrict__ out_wh,
    const __bf16* __restrict__ hmT, const float* __restrict__ hm_b1,
    const __bf16* __restrict__ hm_w2b, const float* __restrict__ hm_b2,
    float* __restrict__ out_hm)
{
    __shared__ __align__(16) char smem[50688];
    const int h = blockIdx.x;
    const int y = blockIdx.y;
    if (y < 4)
        conv_body<2, 0>(smem, X2, idT, id_b1, id_w2b, id_b2, out_id,
                        448, 256, 128, 0, 0, h, y);
    else if (y < 8)
        conv_body<2, 2>(smem, X2, offT, off_b, nullptr, nullptr, off_out,
                        448, 256, 189, 0, 0, h, y - 4);
    else if (y < 36)
        conv_body<2, 1>(smem, X2, whT, wh_b1, wh_w2b, wh_b2, out_wh,
                        64, 256, 2, 0, 1, h, y - 8);
    else
        conv_body<2, 0>(smem, X2, hmT, hm_b1, hm_w2b, hm_b2, out_hm,
                        64, 256, 24, 192, 0, h, y - 36);
}

// ---------------------------------------------------------------------------
// DCNv2 via MFMA + bias + BN + ReLU + bz 1x1, fused.  512 threads / 8 waves
// at (512,6) (best measured: ~220us round 10).  NOW SINGLE-BARRIER PIPELINED:
// double-buffered sC cols + sW tables; per chunk:
//   { B(cc+1)->sC[!cur] | A(cc+2)->sW[cur] | C(cc)<-sC[cur] | one barrier }
// (structure correctness-proven in round 3; its perf confounders — DNP=32,
//  scattered weights — are gone now.)  LDS 51840B -> 3 blocks/CU still fit.
// ---------------------------------------------------------------------------
#define DNP 48
__global__ __launch_bounds__(512, 6) void dcn_bz_mfma(
    const __bf16* __restrict__ X2,
    const float* __restrict__ offmap,   // (B,189,H,W) fp32
    const __bf16* __restrict__ wA,      // [(k/32)*256 + co]*32 + k%32
    const float* __restrict__ dcn_b,
    const float* __restrict__ bn_g, const float* __restrict__ bn_be,
    const float* __restrict__ bn_mn, const float* __restrict__ bn_vr,
    const __bf16* __restrict__ bzwb,    // [16][256]
    const float* __restrict__ bzb,
    float* __restrict__ out_bz)
{
    __shared__ __align__(16) char smem[51840];
    __bf16 (*sC)[6][DNP][40] = (__bf16 (*)[6][DNP][40])smem;   // [2] dbuf cols
    __bf16 (*sD)[DNP][40]    = (__bf16 (*)[DNP][40])smem;      // epilogue alias
    float4 (*sW4)[144] = (float4 (*)[144])(smem + 46080);      // [2][144]
    int    (*sWo)[144] = (int    (*)[144])(smem + 46080 + 4608); // [2][144]

    // XCD-aware bijective swizzle: dispatch order is x-fastest; fid%8 = XCD.
    const int fid = blockIdx.x + blockIdx.y * 192;
    const int nf  = (fid & 7) * 96 + (fid >> 3);
    const int b   = nf / 192;
    const int r_  = nf - b * 192;
    const int h   = r_ >> 1;
    const int w0  = (r_ & 1) * DNP;

    const int t    = threadIdx.x;
    const int wave = t >> 6;           // 0..7
    const int lane = t & 63;
    const int lq   = lane >> 4;
    const int lr   = lane & 15;
    const int mbase = wave * 32;       // 32 co rows per wave
    const int grp  = t >> 3;           // 8-lane gather group 0..63
    const int lsub = t & 7;

    const float* offp = offmap + (size_t)b * 189 * HWSZ;
    const __bf16* Xb  = X2 + ((size_t)b * 96) * 96 * CH2;

    f32x4 acc[2][3];
#pragma unroll
    for (int mi = 0; mi < 2; ++mi)
#pragma unroll
        for (int ni = 0; ni < 3; ++ni)
            acc[mi][ni] = (f32x4){0.f, 0.f, 0.f, 0.f};

    // A: bilinear weights + clamped base for chunk cc -> sW[sel]
    auto Aph = [&](int cc, int sel) {
        if (t < 144) {
            int tl = t / 48;             // kx
            int px = t - tl * 48;
            int pix = h * WW + w0 + px;
            int g = cc / 3, c3 = cc - g * 3;
            int gk  = g * 9 + c3 * 3 + tl;
            float oy = offp[(size_t)gk * HWSZ + pix];
            float ox = offp[(size_t)(63 + gk) * HWSZ + pix];
            float mv = offp[(size_t)(126 + gk) * HWSZ + pix];
            float m  = 1.f / (1.f + expf(-mv));
            float sy = (float)(h - 1 + c3) + oy;
            float sx = (float)(w0 + px - 1 + tl) + ox;
            float fy = floorf(sy), fx = floorf(sx);
            float wy = sy - fy,    wx = sx - fx;
            int y0 = (int)fy, x0 = (int)fx;
            int by = min(max(y0, 0), 94);
            int bx = min(max(x0, 0), 94);
            float wy0 = (y0 == by ? 1.f - wy : 0.f) + (y0 + 1 == by ? wy : 0.f);
            float wy1 = (y0 == by + 1 ? 1.f - wy : 0.f) + (y0 + 1 == by + 1 ? wy : 0.f);
            float wx0 = (x0 == bx ? 1.f - wx : 0.f) + (x0 + 1 == bx ? wx : 0.f);
            float wx1 = (x0 == bx + 1 ? 1.f - wx : 0.f) + (x0 + 1 == bx + 1 ? wx : 0.f);
            float4 wv;
            wv.x = m * wy0 * wx0; wv.y = m * wy0 * wx1;
            wv.z = m * wy1 * wx0; wv.w = m * wy1 * wx1;
            sW4[sel][t] = wv;
            sWo[sel][t] = by * 96 + bx;
        }
    };

    // B: cooperative gather of chunk cc (weights from sW[sel]) -> sC[sel]
    auto Bph = [&](int cc, int sel) {
        const int g = cc / 3;
        for (int p = grp; p < 144; p += 64) {
            float4 wv = sW4[sel][p];
            int base  = sWo[sel][p];
            int tl = p / 48;
            int px = p - tl * 48;
            const __bf16* pl = Xb + (size_t)base * CH2 + g * 64 + lsub * 8;
            bf16x8 c00 = *(const bf16x8*)(pl);
            bf16x8 c01 = *(const bf16x8*)(pl + CH2);
            bf16x8 c10 = *(const bf16x8*)(pl + 96 * CH2);
            bf16x8 c11 = *(const bf16x8*)(pl + 97 * CH2);
            f32x2 vw00 = {wv.x, wv.x}, vw01 = {wv.y, wv.y};
            f32x2 vw10 = {wv.z, wv.z}, vw11 = {wv.w, wv.w};
            const u32* p00 = (const u32*)&c00;
            const u32* p01 = (const u32*)&c01;
            const u32* p10 = (const u32*)&c10;
            const u32* p11 = (const u32*)&c11;
            u32 o[4];
#pragma unroll
            for (int pp = 0; pp < 4; ++pp) {
                f32x2 a = pkmul(vw00, unpk_bf16x2(p00[pp]));
                a = pkfma(vw01, unpk_bf16x2(p01[pp]), a);
                a = pkfma(vw10, unpk_bf16x2(p10[pp]), a);
                a = pkfma(vw11, unpk_bf16x2(p11[pp]), a);
                o[pp] = cvtpk_bf16(a);
            }
            int kc = tl * 2 + (lsub >> 2);
            *(uint4*)&sC[sel][kc][px][(lsub & 3) * 8] = *(const uint4*)o;
        }
    };

    // C: GEMM over chunk cc from sC[sel]
    auto Cph = [&](int cc, int sel) {
        const int g  = cc / 3;
        const int c3 = cc - g * 3;
        const __bf16* wbase = wA + ((size_t)(g * 18 + c3 * 6) * 256 +
                                    mbase + lr) * 32 + lq * 8;
#pragma unroll
        for (int kc = 0; kc < 6; ++kc) {
            const __bf16* wk = wbase + (size_t)kc * 256 * 32;
            bf16x8 aF[2];
#pragma unroll
            for (int mi = 0; mi < 2; ++mi)
                aF[mi] = *(const bf16x8*)(wk + mi * 512);
#pragma unroll
            for (int ni = 0; ni < 3; ++ni) {
                bf16x8 bF = *(const bf16x8*)&sC[sel][kc][ni * 16 + lr][lq * 8];
#pragma unroll
                for (int mi = 0; mi < 2; ++mi)
                    acc[mi][ni] = __builtin_amdgcn_mfma_f32_16x16x32_bf16(
                        aF[mi], bF, acc[mi][ni], 0, 0, 0);
            }
        }
    };

    // ---- prolog ----
    Aph(0, 0);
    __syncthreads();
    Bph(0, 0);
    Aph(1, 1);
    __syncthreads();

    // ---- main loop: ONE barrier per chunk ----
    for (int cc = 0; cc < 21; ++cc) {
        if (cc + 1 < 21) Bph(cc + 1, (cc + 1) & 1);
        if (cc + 2 < 21) Aph(cc + 2, cc & 1);
        Cph(cc, cc & 1);
        __syncthreads();
    }

    // ---- epilogue: bias + BN + relu -> channels-last bf16 LDS -------------
#pragma unroll
    for (int mi = 0; mi < 2; ++mi) {
        int co0 = mbase + mi * 16 + lq * 4;
        float sc[4], sh[4];
#pragma unroll
        for (int r = 0; r < 4; ++r) {
            float s = bn_g[co0 + r] * rsqrtf(bn_vr[co0 + r] + 1e-5f);
            sc[r] = s;
            sh[r] = (dcn_b[co0 + r] - bn_mn[co0 + r]) * s + bn_be[co0 + r];
        }
#pragma unroll
        for (int ni = 0; ni < 3; ++ni) {
            int px = ni * 16 + lr;
            bf16x4 hv;
#pragma unroll
            for (int r = 0; r < 4; ++r)
                hv[r] = (__bf16)fmaxf(acc[mi][ni][r] * sc[r] + sh[r], 0.f);
            *(bf16x4*)&sD[co0 >> 5][px][co0 & 31] = hv;
        }
    }
    __syncthreads();

    // ---- bz 1x1: M=16, K=256, N=48 (3 n-tiles on waves 0..2) --------------
    if (wave < 3) {
        int ni = wave;
        const __bf16* wrow = bzwb + (size_t)lr * 256 + lq * 8;
        f32x4 c = (f32x4){0.f, 0.f, 0.f, 0.f};
#pragma unroll
        for (int kc = 0; kc < 8; ++kc) {
            bf16x8 aF = *(const bf16x8*)(wrow + kc * 32);
            bf16x8 bF = *(const bf16x8*)&sD[kc][ni * 16 + lr][lq * 8];
            c = __builtin_amdgcn_mfma_f32_16x16x32_bf16(aF, bF, c, 0, 0, 0);
        }
        int px = ni * 16 + lr;
#pragma unroll
        for (int r = 0; r < 4; ++r) {
            int cf = lq * 4 + r;
            out_bz[((size_t)(b * 16 + cf)) * HWSZ + h * WW + w0 + px] = c[r] + bzb[cf];
        }
    }
}

// ---------------------------------------------------------------------------
// Launch
// ---------------------------------------------------------------------------
extern "C" void kernel_launch(void* const* d_in, const int* in_sizes, int n_in,
                              void* d_out, int out_size, void* d_ws, size_t ws_size,
                              hipStream_t stream) {
    const float* feat   = (const float*)d_in[0];
    const float* hm_w1  = (const float*)d_in[1];
    const float* hm_b1  = (const float*)d_in[2];
    const float* hm_w2  = (const float*)d_in[3];
    const float* hm_b2  = (const float*)d_in[4];
    const float* wh_w1  = (const float*)d_in[5];
    const float* wh_b1  = (const float*)d_in[6];
    const float* wh_w2  = (const float*)d_in[7];
    const float* wh_b2  = (const float*)d_in[8];
    const float* id_w1  = (const float*)d_in[9];
    const float* id_b1  = (const float*)d_in[10];
    const float* id_w2  = (const float*)d_in[11];
    const float* id_b2  = (const float*)d_in[12];
    const float* off_w  = (const float*)d_in[13];
    const float* off_b  = (const float*)d_in[14];
    const float* dcn_w  = (const float*)d_in[15];
    const float* dcn_b  = (const float*)d_in[16];
    const float* bn_g   = (const float*)d_in[17];
    const float* bn_be  = (const float*)d_in[18];
    const float* bn_mn  = (const float*)d_in[19];
    const float* bn_vr  = (const float*)d_in[20];
    const float* bz_w   = (const float*)d_in[21];
    const float* bz_b   = (const float*)d_in[22];

    // Workspace layout (off_wT2 CoutPad=256: 1,032,192)
    float* ws      = (float*)d_ws;
    float* off_out = ws;                        // 6,967,296 f (27.9 MB)
    __bf16* X2     = (__bf16*)(off_out + 6967296); // 16,515,072 bf16
    __bf16* bfw    = X2 + 16515072;
    __bf16* wh_wT2 = bfw;                       // 147,456
    __bf16* hm_wT2 = wh_wT2 + 147456;           // 147,456
    __bf16* id_wT2 = hm_wT2 + 147456;           // 1,032,192
    __bf16* off_wT2= id_wT2 + 1032192;          // 1,032,192 (padded)
    __bf16* wh_w2b = off_wT2 + 1032192;         //     512
    __bf16* hm_w2b = wh_w2b + 512;              //    6144
    __bf16* id_w2b = hm_w2b + 6144;             //   32768
    __bf16* dcn_wA = id_w2b + 32768;            // 1,032,192
    __bf16* bz_wb  = dcn_wA + 1032192;          //    4096

    // Output layout (floats, concatenated): hm, bz, idout, owh
    float* out_hm = (float*)d_out;              // (4,24,96,96)
    float* out_bz = out_hm + 884736;            // (4,16,96,96)
    float* out_id = out_bz + 589824;            // (4,128,96,96)
    float* out_wh = out_id + 4718592;           // (4,14,96,96)

    // 1) ONE prep dispatch (feat conversion + all weight transforms)
    prep_all<<<15051, 256, 0, stream>>>(
        feat, X2,
        wh_w1, wh_wT2, hm_w1, hm_wT2, id_w1, id_wT2, off_w, off_wT2,
        wh_w2, wh_w2b, hm_w2, hm_w2b, id_w2, id_w2b, bz_w, bz_wb,
        dcn_w, dcn_wA);

    // 2) ALL conv branches in one dispatch (8-wave MPW=2, (512,4))
    conv_all<<<dim3(96, 40), 512, 0, stream>>>(
        X2,
        id_wT2, id_b1, id_w2b, id_b2, out_id,
        off_wT2, off_b, off_out,
        wh_wT2, wh_b1, wh_w2b, wh_b2, out_wh,
        hm_wT2, hm_b1, hm_w2b, hm_b2, out_hm);

    // 3) DCN via MFMA + BN + ReLU + bz ((512,6), single-barrier pipeline)
    dcn_bz_mfma<<<dim3(192, 4), 512, 0, stream>>>(
        X2, off_out, dcn_wA, dcn_b, bn_g, bn_be, bn_mn, bn_vr,
        bz_wb, bz_b, out_bz);
}